// Round 1
// baseline (15293.629 us; speedup 1.0000x reference)
//
#include <hip/hip_runtime.h>
#include <hip/hip_bf16.h>

// Problem: B=16, N=2048, D=64, fp32 in/out.
// scores[b,q,k] = (Q[b,q,:]·K[b,k,:]) / 8 ; softmax over b (batch!) ;
// out[b,q,d] = sum_k attn[b,q,k] * V[b,k,d].
// Softmax axis is the batch dim (16) -> fully thread-local per (q,k).

#define BATCH 16
#define SEQ   2048
#define DIM   64
#define QT    8     // q rows per block
#define KT    64    // k cols per tile (== one wave's lanes)

__global__ __launch_bounds__(512)
void dpa_kernel(const float* __restrict__ Q,
                const float* __restrict__ K,
                const float* __restrict__ V,
                float* __restrict__ out) {
    // attn handoff: [b][q][k] fp32. Score-phase writes are consecutive-k per
    // wave (conflict-free); PV-phase reads are wave-uniform (broadcast).
    __shared__ float attn_lds[BATCH][QT][KT];

    const int tid = threadIdx.x;
    const int lane_k = tid & 63;   // score phase: k within tile
    const int row_q  = tid >> 6;   // 0..7 : q within tile (both phases)
    const int lane_d = tid & 63;   // PV phase: d index
    const int q0 = blockIdx.x * QT;

    const float scale = 0.125f;   // 1/sqrt(64)

    float acc[BATCH];
    #pragma unroll
    for (int b = 0; b < BATCH; ++b) acc[b] = 0.0f;

    for (int k0 = 0; k0 < SEQ; k0 += KT) {
        // ---- score phase: thread = (row_q, lane_k) ----
        float s[BATCH];
        #pragma unroll
        for (int b = 0; b < BATCH; ++b) {
            const float4* qrow = (const float4*)(Q + ((size_t)b * SEQ + (q0 + row_q)) * DIM);
            const float4* krow = (const float4*)(K + ((size_t)b * SEQ + (k0 + lane_k)) * DIM);
            float a0 = 0.f, a1 = 0.f, a2 = 0.f, a3 = 0.f;
            #pragma unroll
            for (int d4 = 0; d4 < DIM / 4; ++d4) {
                float4 qa = qrow[d4];
                float4 kb = krow[d4];
                a0 += qa.x * kb.x;
                a1 += qa.y * kb.y;
                a2 += qa.z * kb.z;
                a3 += qa.w * kb.w;
            }
            s[b] = (a0 + a1 + a2 + a3) * scale;
        }
        // thread-local softmax over the 16 batches
        float m = s[0];
        #pragma unroll
        for (int b = 1; b < BATCH; ++b) m = fmaxf(m, s[b]);
        float denom = 0.f;
        #pragma unroll
        for (int b = 0; b < BATCH; ++b) {
            s[b] = __expf(s[b] - m);
            denom += s[b];
        }
        const float inv = 1.0f / denom;
        #pragma unroll
        for (int b = 0; b < BATCH; ++b)
            attn_lds[b][row_q][lane_k] = s[b] * inv;

        __syncthreads();

        // ---- PV phase: thread = (row_q, lane_d) ----
        #pragma unroll
        for (int b = 0; b < BATCH; ++b) {
            const float* vbase = V + ((size_t)b * SEQ + k0) * DIM + lane_d;
            float a = 0.f;
            #pragma unroll 8
            for (int kk = 0; kk < KT; ++kk) {
                a += attn_lds[b][row_q][kk] * vbase[(size_t)kk * DIM];
            }
            acc[b] += a;
        }

        __syncthreads();
    }

    #pragma unroll
    for (int b = 0; b < BATCH; ++b)
        out[((size_t)b * SEQ + (q0 + row_q)) * DIM + lane_d] = acc[b];
}

extern "C" void kernel_launch(void* const* d_in, const int* in_sizes, int n_in,
                              void* d_out, int out_size, void* d_ws, size_t ws_size,
                              hipStream_t stream) {
    const float* Q = (const float*)d_in[0];
    const float* K = (const float*)d_in[1];
    const float* V = (const float*)d_in[2];
    float* out = (float*)d_out;

    dim3 grid(SEQ / QT);   // 256 blocks
    dim3 block(512);       // 8 waves
    dpa_kernel<<<grid, block, 0, stream>>>(Q, K, V, out);
}

// Round 2
// 790.353 us; speedup vs baseline: 19.3504x; 19.3504x over previous
//
#include <hip/hip_runtime.h>
#include <hip/hip_bf16.h>

// B=16, N=2048, D=64 fp32. scores = QK^T/8; softmax over BATCH dim; out = attn·V.
// Softmax over b is lane-local in MFMA C-layout: same lane/reg slot across the
// 16 per-batch accumulators = same (q,k). Grid 256 = 64 q-tiles x 4 batch-groups
// (QK^T recomputed per group; PV split 4 batches/block). 4 waves = 2m x 2k.

typedef __attribute__((ext_vector_type(8))) short short8;
typedef __attribute__((ext_vector_type(4))) short short4v;
typedef __attribute__((ext_vector_type(4))) unsigned short ushort4v;
typedef __attribute__((ext_vector_type(4))) float floatx4;

#define BATCH 16
#define SEQ   2048
#define DIM   64
#define QB    32
#define KBT   32
#define NT    (SEQ/KBT)

// LDS map (bytes). K half-region: [8 b][32 k][128B row, XOR-swizzled]
#define KB_B  4096
#define VOFF  32768          // V: [4 b][4 dsub][8 quad][16 dd][4 kq]
#define V_B   4416
#define V_DS  1104
#define V_QD  136
#define POFF  50432          // P^T: [4 b][8 quad][32 q][4 kq]
#define P_B   2112
#define P_QD  264
#define LDS_BYTES 58880

__device__ __forceinline__ unsigned short f2bf(float f) {
    return __builtin_bit_cast(unsigned short, __float2bfloat16(f));
}

__global__ __launch_bounds__(256, 1)
void dpa_mfma(const float* __restrict__ Qg, const float* __restrict__ Kg,
              const float* __restrict__ Vg, float* __restrict__ Og) {
    __shared__ __align__(16) unsigned char lds[LDS_BYTES];

    const int tid = threadIdx.x;
    const int l   = tid & 63;
    const int w   = tid >> 6;      // wave 0..3
    const int wm  = w >> 1;        // m-half (q)
    const int wk  = w & 1;         // k-half (QK^T) / d-half (PV)
    const int a   = l & 15;
    const int g   = l >> 4;

    const int qt  = blockIdx.x & 63;
    const int bg  = blockIdx.x >> 6;     // bg-major => siblings share XCD (bx%8 = qt%8)
    const int q0  = qt * QB;
    const int vb0 = bg * 4;

    // staging thread mapping
    const int kr = tid >> 4;       // 0..15
    const int d4 = tid & 15;

    // ---- preload Q fragments into VGPRs: Qf[b][h], elem p <-> d = 32h+8g+p ----
    short8 Qf[BATCH][2];
    {
        const int qrow = q0 + wm * 16 + a;
        #pragma unroll
        for (int b = 0; b < BATCH; ++b) {
            #pragma unroll
            for (int h = 0; h < 2; ++h) {
                const float* src = Qg + ((size_t)(b * SEQ + qrow)) * DIM + h * 32 + g * 8;
                const float4 f0 = *(const float4*)(src);
                const float4 f1 = *(const float4*)(src + 4);
                short8 q;
                q[0] = (short)f2bf(f0.x); q[1] = (short)f2bf(f0.y);
                q[2] = (short)f2bf(f0.z); q[3] = (short)f2bf(f0.w);
                q[4] = (short)f2bf(f1.x); q[5] = (short)f2bf(f1.y);
                q[6] = (short)f2bf(f1.z); q[7] = (short)f2bf(f1.w);
                Qf[b][h] = q;
            }
        }
    }

    floatx4 Oacc[4][2];
    #pragma unroll
    for (int bp = 0; bp < 4; ++bp) {
        Oacc[bp][0] = (floatx4)0.0f;
        Oacc[bp][1] = (floatx4)0.0f;
    }

    for (int kt = 0; kt < NT; ++kt) {
        const int kg0 = kt * KBT;

        floatx4 S[BATCH];
        #pragma unroll
        for (int b = 0; b < BATCH; ++b) S[b] = (floatx4)0.0f;

        // ---------------- stage K batches 0..7 ----------------
        #pragma unroll
        for (int bi = 0; bi < 8; ++bi) {
            #pragma unroll
            for (int i = 0; i < 2; ++i) {
                const int k = i * 16 + kr;
                const float4 f = *(const float4*)(Kg + ((size_t)(bi * SEQ + kg0 + k)) * DIM + d4 * 4);
                ushort4v u;
                u[0] = f2bf(f.x); u[1] = f2bf(f.y); u[2] = f2bf(f.z); u[3] = f2bf(f.w);
                *(ushort4v*)(lds + bi * KB_B + k * 128 + ((d4 * 8) ^ ((k & 7) << 4))) = u;
            }
        }
        __syncthreads();

        // ---------------- QK^T batches 0..7 ----------------
        {
            const int krow = wk * 16 + a;   // (krow&7)==(a&7), matches write swizzle
            #pragma unroll
            for (int bi = 0; bi < 8; ++bi) {
                #pragma unroll
                for (int h = 0; h < 2; ++h) {
                    const short8 kf = *(const short8*)(lds + bi * KB_B + krow * 128 +
                                                      ((h * 64 + g * 16) ^ ((a & 7) << 4)));
                    S[bi] = __builtin_amdgcn_mfma_f32_16x16x32_bf16(Qf[bi][h], kf, S[bi], 0, 0, 0);
                }
            }
        }
        __syncthreads();

        // ---------------- stage K batches 8..15 + stage V (4 batches) ----------------
        #pragma unroll
        for (int bi = 0; bi < 8; ++bi) {
            #pragma unroll
            for (int i = 0; i < 2; ++i) {
                const int k = i * 16 + kr;
                const float4 f = *(const float4*)(Kg + ((size_t)((8 + bi) * SEQ + kg0 + k)) * DIM + d4 * 4);
                ushort4v u;
                u[0] = f2bf(f.x); u[1] = f2bf(f.y); u[2] = f2bf(f.z); u[3] = f2bf(f.w);
                *(ushort4v*)(lds + bi * KB_B + k * 128 + ((d4 * 8) ^ ((k & 7) << 4))) = u;
            }
        }
        {
            const int d0  = d4 * 4;
            const int ds  = d0 >> 4;
            const int dd0 = d0 & 15;
            #pragma unroll
            for (int bp = 0; bp < 4; ++bp) {
                #pragma unroll
                for (int i = 0; i < 2; ++i) {
                    const int k = i * 16 + kr;
                    const float4 f = *(const float4*)(Vg + ((size_t)((vb0 + bp) * SEQ + kg0 + k)) * DIM + d0);
                    unsigned char* base = lds + VOFF + bp * V_B + ds * V_DS + (k >> 2) * V_QD + (k & 3) * 2;
                    *(unsigned short*)(base + (dd0 + 0) * 8) = f2bf(f.x);
                    *(unsigned short*)(base + (dd0 + 1) * 8) = f2bf(f.y);
                    *(unsigned short*)(base + (dd0 + 2) * 8) = f2bf(f.z);
                    *(unsigned short*)(base + (dd0 + 3) * 8) = f2bf(f.w);
                }
            }
        }
        __syncthreads();

        // ---------------- QK^T batches 8..15 ----------------
        {
            const int krow = wk * 16 + a;
            #pragma unroll
            for (int bi = 0; bi < 8; ++bi) {
                #pragma unroll
                for (int h = 0; h < 2; ++h) {
                    const short8 kf = *(const short8*)(lds + bi * KB_B + krow * 128 +
                                                      ((h * 64 + g * 16) ^ ((a & 7) << 4)));
                    S[8 + bi] = __builtin_amdgcn_mfma_f32_16x16x32_bf16(Qf[8 + bi][h], kf, S[8 + bi], 0, 0, 0);
                }
            }
        }

        // ---------------- softmax over batch (lane-local) + write P^T ----------------
        {
            const int kq = wk * 16 + a;
            #pragma unroll
            for (int r = 0; r < 4; ++r) {
                float m = S[0][r];
                #pragma unroll
                for (int b = 1; b < BATCH; ++b) m = fmaxf(m, S[b][r]);
                float p[BATCH];
                float den = 0.0f;
                #pragma unroll
                for (int b = 0; b < BATCH; ++b) {
                    p[b] = __expf((S[b][r] - m) * 0.125f);
                    den += p[b];
                }
                const float inv = 1.0f / den;
                const int qq = wm * 16 + g * 4 + r;
                #pragma unroll
                for (int bp = 0; bp < 4; ++bp) {
                    *(unsigned short*)(lds + POFF + bp * P_B + (kq >> 2) * P_QD + qq * 8 + (kq & 3) * 2)
                        = f2bf(p[vb0 + bp] * inv);
                }
            }
        }
        __syncthreads();

        // ---------------- PV: O[b'] += P[b'] · V[b'] ----------------
        {
            const int qoff = (wm * 16 + a) * 8;
            #pragma unroll
            for (int bp = 0; bp < 4; ++bp) {
                const unsigned char* pb = lds + POFF + bp * P_B;
                const short4v plo = *(const short4v*)(pb + (2 * g + 0) * P_QD + qoff);
                const short4v phi = *(const short4v*)(pb + (2 * g + 1) * P_QD + qoff);
                const short8 af = __builtin_shufflevector(plo, phi, 0, 1, 2, 3, 4, 5, 6, 7);
                #pragma unroll
                for (int dsi = 0; dsi < 2; ++dsi) {
                    const int ds = wk * 2 + dsi;
                    const unsigned char* vb = lds + VOFF + bp * V_B + ds * V_DS + a * 8;
                    const short4v vlo = *(const short4v*)(vb + (2 * g + 0) * V_QD);
                    const short4v vhi = *(const short4v*)(vb + (2 * g + 1) * V_QD);
                    const short8 bf = __builtin_shufflevector(vlo, vhi, 0, 1, 2, 3, 4, 5, 6, 7);
                    Oacc[bp][dsi] = __builtin_amdgcn_mfma_f32_16x16x32_bf16(af, bf, Oacc[bp][dsi], 0, 0, 0);
                }
            }
        }
        // no trailing barrier: next iteration's first barrier protects V/P^T regions
    }

    // ---------------- store O ----------------
    #pragma unroll
    for (int bp = 0; bp < 4; ++bp) {
        #pragma unroll
        for (int dsi = 0; dsi < 2; ++dsi) {
            #pragma unroll
            for (int r = 0; r < 4; ++r) {
                Og[((size_t)((vb0 + bp) * SEQ + q0 + wm * 16 + g * 4 + r)) * DIM + (wk * 2 + dsi) * 16 + a]
                    = Oacc[bp][dsi][r];
            }
        }
    }
}

extern "C" void kernel_launch(void* const* d_in, const int* in_sizes, int n_in,
                              void* d_out, int out_size, void* d_ws, size_t ws_size,
                              hipStream_t stream) {
    const float* Q = (const float*)d_in[0];
    const float* K = (const float*)d_in[1];
    const float* V = (const float*)d_in[2];
    float* out = (float*)d_out;

    dpa_mfma<<<dim3(256), dim3(256), 0, stream>>>(Q, K, V, out);
}

// Round 3
// 166.927 us; speedup vs baseline: 91.6187x; 4.7347x over previous
//
#include <hip/hip_runtime.h>
#include <hip/hip_bf16.h>

typedef __attribute__((ext_vector_type(8))) short short8;
typedef __attribute__((ext_vector_type(4))) float floatx4;

#define BATCH 16
#define SEQ   2048
#define DIM   64
#define WS_NEED (12u*1024u*1024u)

__device__ __forceinline__ unsigned short f2bf(float f) {
    return __builtin_bit_cast(unsigned short, __float2bfloat16(f));
}

// ---------------- convert: fp32 -> bf16 in MFMA-frag-ready layouts ----------------
// Qw [16][128 qt][2 st][64 l][8 p]  = Q[b][qt*16+a][st*32+g*8+p] * 0.125   (a=l&15,g=l>>4)
// Kw same layout (no scale), k-tiles of 16.
// Vw [16][64 kt2][4 ds][64 l][8 p]  = V[b][kt2*32+g*8+p][ds*16+a]
__global__ __launch_bounds__(256)
void convert_kernel(const float* __restrict__ Q, const float* __restrict__ K,
                    const float* __restrict__ V, unsigned short* __restrict__ ws) {
    const int t = blockIdx.x * 256 + threadIdx.x;   // 0..786431
    const int region = t >> 18;                     // 0=Q 1=K 2=V
    const int r = t & 262143;
    const int b = r >> 14;
    short8 o;
    if (region < 2) {
        const int rem  = r & 16383;
        const int t16  = rem >> 7;
        const int st   = (rem >> 6) & 1;
        const int l    = rem & 63;
        const int a = l & 15, g = l >> 4;
        const float* src = (region == 0 ? Q : K) +
            ((size_t)(b * SEQ + t16 * 16 + a)) * DIM + st * 32 + g * 8;
        const float s = (region == 0) ? 0.125f : 1.0f;
        #pragma unroll
        for (int p = 0; p < 8; ++p) o[p] = (short)f2bf(src[p] * s);
    } else {
        const int rem  = r & 16383;
        const int kt2  = rem >> 8;
        const int ds   = (rem >> 6) & 3;
        const int l    = rem & 63;
        const int a = l & 15, g = l >> 4;
        const float* src = V + ((size_t)(b * SEQ + kt2 * 32 + g * 8)) * DIM + ds * 16 + a;
        #pragma unroll
        for (int p = 0; p < 8; ++p) o[p] = (short)f2bf(src[(size_t)p * DIM]);
    }
    *(short8*)(ws + (size_t)region * 2097152 + (size_t)r * 8) = o;
}

// ---------------- main: split-k attention, softmax over batch ----------------
// grid 512 = 128 q-tiles(16 rows) x 4 k-chunks(512). block 256 = 4 waves:
// bg = w&1 (batches bg*8..+8), ks = w>>1 (k-sub 16 in QKT / 32-d half in PV).
// P LDS handoff: rows of 128B (2 batches/row), chunk-XOR swizzle by (q&7).
__device__ __forceinline__ int pl_byte(int buf, int b, int q, int chunk) {
    // chunk = (b&1)*4 + (k>>3); swizzled by q&7; returns byte offset of 16B chunk
    return ((buf * 8 + (b >> 1)) * 16 + q) * 128 + ((chunk ^ (q & 7)) * 16);
}

__global__ __launch_bounds__(256, 2)
void dpa_main(const unsigned short* __restrict__ Qw, const unsigned short* __restrict__ Kw,
              const unsigned short* __restrict__ Vw, float* __restrict__ Og) {
    __shared__ __align__(16) unsigned char Pl[32768];        // [2][8 bp][16 q][128B]
    __shared__ float mdl[2][2][16][32][2];                   // [buf][bg][q][k][m,d]

    const int tid = threadIdx.x;
    const int l  = tid & 63;
    const int w  = tid >> 6;
    const int bg = w & 1;
    const int ks = w >> 1;          // 0..1
    const int a = l & 15, g = l >> 4;
    const int bx = blockIdx.x;
    const int ch = (bx & 7) >> 1;                       // chunk 0..3 (XCD-paired)
    const int qt = ((bx >> 3) << 1) | (bx & 1);         // 0..127
    const int b0 = bg * 8;

    // Q fragments in registers (shared by both k-sub waves of this bg)
    short8 Qf[8][2];
    #pragma unroll
    for (int bb = 0; bb < 8; ++bb)
        #pragma unroll
        for (int st = 0; st < 2; ++st)
            Qf[bb][st] = *(const short8*)(Qw +
                ((size_t)(((b0 + bb) * 128 + qt) * 2 + st)) * 512 + l * 8);

    floatx4 O[8][2];
    #pragma unroll
    for (int bb = 0; bb < 8; ++bb) { O[bb][0] = (floatx4)0.0f; O[bb][1] = (floatx4)0.0f; }

    const int kloc = ks * 16 + a;

    for (int it = 0; it < 16; ++it) {
        const int buf = it & 1;

        // ---- QK^T: frag-direct global K loads ----
        floatx4 S[8];
        #pragma unroll
        for (int bb = 0; bb < 8; ++bb) S[bb] = (floatx4)0.0f;
        const int kt16 = ch * 32 + it * 2 + ks;
        #pragma unroll
        for (int bb = 0; bb < 8; ++bb) {
            #pragma unroll
            for (int st = 0; st < 2; ++st) {
                const short8 Kf = *(const short8*)(Kw +
                    ((size_t)(((b0 + bb) * 128 + kt16) * 2 + st)) * 512 + l * 8);
                S[bb] = __builtin_amdgcn_mfma_f32_16x16x32_bf16(Qf[bb][st], Kf, S[bb], 0, 0, 0);
            }
        }

        // ---- softmax over batch: 8-local + cross-bg (m,d) exchange ----
        float m8[4], d8[4];
        #pragma unroll
        for (int r = 0; r < 4; ++r) {
            float m = S[0][r];
            #pragma unroll
            for (int bb = 1; bb < 8; ++bb) m = fmaxf(m, S[bb][r]);
            float dsum = 0.0f;
            #pragma unroll
            for (int bb = 0; bb < 8; ++bb) {
                const float ev = __expf(S[bb][r] - m);   // scores pre-scaled via Q
                S[bb][r] = ev;
                dsum += ev;
            }
            m8[r] = m; d8[r] = dsum;
            const int q = g * 4 + r;
            mdl[buf][bg][q][kloc][0] = m;
            mdl[buf][bg][q][kloc][1] = dsum;
        }
        __syncthreads();
        #pragma unroll
        for (int r = 0; r < 4; ++r) {
            const int q = g * 4 + r;
            const float mo  = mdl[buf][bg ^ 1][q][kloc][0];
            const float dho = mdl[buf][bg ^ 1][q][kloc][1];
            const float m   = fmaxf(m8[r], mo);
            const float cs  = __expf(m8[r] - m);
            const float co  = __expf(mo - m);
            const float inv = cs / (d8[r] * cs + dho * co);
            #pragma unroll
            for (int bb = 0; bb < 8; ++bb) {
                const int b = b0 + bb;
                const int chunk = (b & 1) * 4 + (kloc >> 3);
                *(unsigned short*)(Pl + pl_byte(buf, b, q, chunk) + (kloc & 7) * 2)
                    = f2bf(S[bb][r] * inv);
            }
        }
        __syncthreads();

        // ---- PV: P from LDS (swizzled b128), V frag-direct from global ----
        const int kt2 = ch * 16 + it;
        #pragma unroll
        for (int bb = 0; bb < 8; ++bb) {
            const int b = b0 + bb;
            const short8 Pf = *(const short8*)(Pl + pl_byte(buf, b, a, (b & 1) * 4 + g));
            #pragma unroll
            for (int j = 0; j < 2; ++j) {
                const int dsub = ks * 2 + j;
                const short8 Vf = *(const short8*)(Vw +
                    ((size_t)(((b * 64 + kt2) * 4 + dsub)) * 512) + l * 8);
                O[bb][j] = __builtin_amdgcn_mfma_f32_16x16x32_bf16(Pf, Vf, O[bb][j], 0, 0, 0);
            }
        }
        // no trailing barrier: buf parity + next iter's barriers protect reuse
    }

    // ---- accumulate partials into d_out (zeroed by memset each launch) ----
    #pragma unroll
    for (int bb = 0; bb < 8; ++bb)
        #pragma unroll
        for (int j = 0; j < 2; ++j)
            #pragma unroll
            for (int r = 0; r < 4; ++r)
                atomicAdd(Og + ((size_t)((b0 + bb) * SEQ + qt * 16 + g * 4 + r)) * DIM
                              + ks * 32 + j * 16 + a,
                          O[bb][j][r]);
}

// ---------------- fallback (ws too small): naive fp32, correct but slow ----------------
__global__ __launch_bounds__(512)
void dpa_naive(const float* __restrict__ Q, const float* __restrict__ K,
               const float* __restrict__ V, float* __restrict__ out) {
    __shared__ float attn_lds[BATCH][8][64];
    const int tid = threadIdx.x;
    const int lane_k = tid & 63, row_q = tid >> 6, lane_d = tid & 63;
    const int q0 = blockIdx.x * 8;
    float acc[BATCH];
    #pragma unroll
    for (int b = 0; b < BATCH; ++b) acc[b] = 0.0f;
    for (int k0 = 0; k0 < SEQ; k0 += 64) {
        float s[BATCH];
        #pragma unroll
        for (int b = 0; b < BATCH; ++b) {
            const float4* qrow = (const float4*)(Q + ((size_t)b * SEQ + (q0 + row_q)) * DIM);
            const float4* krow = (const float4*)(K + ((size_t)b * SEQ + (k0 + lane_k)) * DIM);
            float a0 = 0.f;
            #pragma unroll
            for (int d4 = 0; d4 < 16; ++d4) {
                float4 qa = qrow[d4]; float4 kb = krow[d4];
                a0 += qa.x*kb.x + qa.y*kb.y + qa.z*kb.z + qa.w*kb.w;
            }
            s[b] = a0 * 0.125f;
        }
        float m = s[0];
        #pragma unroll
        for (int b = 1; b < BATCH; ++b) m = fmaxf(m, s[b]);
        float den = 0.f;
        #pragma unroll
        for (int b = 0; b < BATCH; ++b) { s[b] = __expf(s[b] - m); den += s[b]; }
        const float inv = 1.0f / den;
        #pragma unroll
        for (int b = 0; b < BATCH; ++b) attn_lds[b][row_q][lane_k] = s[b] * inv;
        __syncthreads();
        #pragma unroll
        for (int b = 0; b < BATCH; ++b) {
            const float* vbase = V + ((size_t)b * SEQ + k0) * DIM + lane_d;
            float acc2 = 0.f;
            #pragma unroll 8
            for (int kk = 0; kk < 64; ++kk) acc2 += attn_lds[b][row_q][kk] * vbase[(size_t)kk * DIM];
            acc[b] += acc2;
        }
        __syncthreads();
    }
    #pragma unroll
    for (int b = 0; b < BATCH; ++b)
        out[((size_t)b * SEQ + (q0 + row_q)) * DIM + lane_d] = acc[b];
}

extern "C" void kernel_launch(void* const* d_in, const int* in_sizes, int n_in,
                              void* d_out, int out_size, void* d_ws, size_t ws_size,
                              hipStream_t stream) {
    const float* Q = (const float*)d_in[0];
    const float* K = (const float*)d_in[1];
    const float* V = (const float*)d_in[2];
    float* out = (float*)d_out;

    if (ws_size < WS_NEED) {
        dpa_naive<<<dim3(SEQ / 8), dim3(512), 0, stream>>>(Q, K, V, out);
        return;
    }
    unsigned short* ws = (unsigned short*)d_ws;
    hipMemsetAsync(d_out, 0, (size_t)out_size * sizeof(float), stream);
    convert_kernel<<<dim3(3072), dim3(256), 0, stream>>>(Q, K, V, ws);
    dpa_main<<<dim3(512), dim3(256), 0, stream>>>(ws, ws + 2097152, ws + 4194304, out);
}

// Round 4
// 152.186 us; speedup vs baseline: 100.4931x; 1.0969x over previous
//
#include <hip/hip_runtime.h>
#include <hip/hip_bf16.h>

typedef __attribute__((ext_vector_type(8))) short short8;
typedef __attribute__((ext_vector_type(4))) short short4v;
typedef __attribute__((ext_vector_type(2))) int   int2v;
typedef __attribute__((ext_vector_type(4))) float floatx4;

#define BATCH 16
#define SEQ   2048
#define DIM   64
#define QSCALE 0.18033688011112042f   /* 0.125 * log2(e) : softmax done in exp2 domain */
#define WS_NEED (12u*1024u*1024u)

__device__ __forceinline__ unsigned short f2bf(float f) {
    return __builtin_bit_cast(unsigned short, __float2bfloat16(f));
}

// ---- K=16 bf16 MFMA: prefer intrinsic, fall back to inline asm ----
#if defined(__has_builtin)
#if __has_builtin(__builtin_amdgcn_mfma_f32_16x16x16bf16_1k)
#define MFMA16(A,B,C) __builtin_amdgcn_mfma_f32_16x16x16bf16_1k(A,B,C,0,0,0)
#elif __has_builtin(__builtin_amdgcn_mfma_f32_16x16x16_bf16)
#define MFMA16(A,B,C) __builtin_amdgcn_mfma_f32_16x16x16_bf16(A,B,C,0,0,0)
#endif
#endif
#ifndef MFMA16
__device__ __forceinline__ floatx4 mfma16_asm(short4v a, short4v b, floatx4 c) {
    asm volatile("s_nop 1\n\tv_mfma_f32_16x16x16_bf16 %0, %1, %2, %0"
                 : "+v"(c) : "v"(a), "v"(b));
    return c;
}
#define MFMA16(A,B,C) mfma16_asm(A,B,C)
#endif

// ---------------- convert: fp32 -> bf16 MFMA-frag layouts ----------------
// Qw [16][128 t16][2 st][64 l][8p] = Q[b][t16*16+a][st*32+g*8+p] * QSCALE  (a=l&15,g=l>>4)
// Kw same (scale 1).     (A/B frag for 16x16x32: row/col=a, k=g*8+p)
// Vw [16][128 kt][64 l][4 dt][4p] = V[b][kt*16+g*4+p][dt*16+a]   (B frag for 16x16x16)
__global__ __launch_bounds__(256)
void convert_kernel(const float* __restrict__ Q, const float* __restrict__ K,
                    const float* __restrict__ V, unsigned short* __restrict__ ws) {
    const int t = blockIdx.x * 256 + threadIdx.x;   // 0..655359
    if (t < 524288) {
        const int region = t >> 18;                 // 0=Q 1=K
        const int r = t & 262143;
        const int b = r >> 14;
        const int rem = r & 16383;
        const int t16 = rem >> 7;
        const int st  = (rem >> 6) & 1;
        const int l   = rem & 63;
        const int a = l & 15, g = l >> 4;
        const float* src = (region == 0 ? Q : K) +
            ((size_t)(b * SEQ + t16 * 16 + a)) * DIM + st * 32 + g * 8;
        const float s = (region == 0) ? QSCALE : 1.0f;
        short8 o;
        #pragma unroll
        for (int p = 0; p < 8; ++p) o[p] = (short)f2bf(src[p] * s);
        *(short8*)(ws + (size_t)region * 2097152 + (size_t)r * 8) = o;
    } else {
        const int r = t - 524288;                   // 0..131071 = [b][kt][l]
        const int b  = r >> 13;
        const int kt = (r >> 6) & 127;
        const int l  = r & 63;
        const int a = l & 15, g = l >> 4;
        const float* src = V + ((size_t)(b * SEQ + kt * 16 + g * 4)) * DIM + a;
        short8 o0, o1;
        #pragma unroll
        for (int dt = 0; dt < 2; ++dt)
            #pragma unroll
            for (int p = 0; p < 4; ++p)
                o0[dt * 4 + p] = (short)f2bf(src[(size_t)p * DIM + dt * 16]);
        #pragma unroll
        for (int dt = 2; dt < 4; ++dt)
            #pragma unroll
            for (int p = 0; p < 4; ++p)
                o1[(dt - 2) * 4 + p] = (short)f2bf(src[(size_t)p * DIM + dt * 16]);
        unsigned short* dst = ws + 4194304 + (size_t)r * 16;
        *(short8*)(dst)     = o0;
        *(short8*)(dst + 8) = o1;
    }
}

// ---------------- main: softmax-over-batch attention ----------------
// grid 1024 = 128 q-tiles(16) x 8 k-chunks(256).  ch = bx&7 -> one chunk per XCD.
// block 256 = 4 waves = 4 batch-quarters. Swapped QK^T (mfma(K,Q)) puts
// P^T[k=g*4+r][q=a] in registers == the A-frag of 16x16x16 PV. Only the
// softmax denominator crosses waves (1 barrier/iter, double-buffered LDS).
__global__ __launch_bounds__(256)
void dpa_main(const unsigned short* __restrict__ Qw, const unsigned short* __restrict__ Kw,
              const unsigned short* __restrict__ Vw, float* __restrict__ Og) {
    __shared__ __align__(16) unsigned short Qlds[16384];   // 32 KB: [16b][2st][64l][8p]
    __shared__ float dl[2][4][4][64];                      // 8 KB: [buf][wave][r][lane]

    const int tid = threadIdx.x;
    const int l = tid & 63;
    const int w = tid >> 6;            // batch-quarter 0..3
    const int a = l & 15, g = l >> 4;
    const int bx = blockIdx.x;
    const int ch = bx & 7;
    const int qt = bx >> 3;
    const int b0 = w * 4;

    // stage Q frags (all 16 b for this q-tile) into LDS, coalesced
    #pragma unroll
    for (int i = 0; i < 8; ++i) {
        const int f = i * 256 + tid;               // ((b*2+st)*64 + l)
        const int qb = f >> 7;
        const int rest = f & 127;                  // st*64 + l
        *(short8*)(Qlds + f * 8) =
            *(const short8*)(Qw + ((size_t)((qb * 128 + qt) * 128 + rest)) * 8);
    }

    floatx4 O[4][4];
    #pragma unroll
    for (int bb = 0; bb < 4; ++bb)
        #pragma unroll
        for (int dt = 0; dt < 4; ++dt) O[bb][dt] = (floatx4)0.0f;

    __syncthreads();

    #pragma unroll 2
    for (int it = 0; it < 16; ++it) {
        const int buf = it & 1;
        const int kt = ch * 16 + it;

        // ---- QK^T (swapped): S[b] = K_frag x Q_frag -> S^T[k=g*4+r][q=a] ----
        floatx4 S[4];
        #pragma unroll
        for (int bb = 0; bb < 4; ++bb) {
            S[bb] = (floatx4)0.0f;
            #pragma unroll
            for (int st = 0; st < 2; ++st) {
                const short8 Kf = *(const short8*)(Kw +
                    ((size_t)(((b0 + bb) * 128 + kt) * 128 + st * 64 + l)) * 8);
                const short8 Qf = *(const short8*)(Qlds + ((b0 + bb) * 128 + st * 64 + l) * 8);
                S[bb] = __builtin_amdgcn_mfma_f32_16x16x32_bf16(Kf, Qf, S[bb], 0, 0, 0);
            }
        }

        // ---- local softmax partial (no max-subtraction: |S|<~10 in log2 domain) ----
        #pragma unroll
        for (int r = 0; r < 4; ++r) {
            float e0 = exp2f(S[0][r]);
            float e1 = exp2f(S[1][r]);
            float e2 = exp2f(S[2][r]);
            float e3 = exp2f(S[3][r]);
            S[0][r] = e0; S[1][r] = e1; S[2][r] = e2; S[3][r] = e3;
            dl[buf][w][r][l] = (e0 + e1) + (e2 + e3);
        }
        __syncthreads();

        // ---- combine denominators + finalize P + PV ----
        float fr[4];
        #pragma unroll
        for (int r = 0; r < 4; ++r) {
            const float den = (dl[buf][0][r][l] + dl[buf][1][r][l]) +
                              (dl[buf][2][r][l] + dl[buf][3][r][l]);
            fr[r] = __builtin_amdgcn_rcpf(den);
        }

        #pragma unroll
        for (int bb = 0; bb < 4; ++bb) {
            // V frag loads (2 x 16B covers all 4 d-tiles)
            const unsigned short* vb = Vw + ((size_t)(((b0 + bb) * 128 + kt) * 64 + l)) * 16;
            const short8 v01 = *(const short8*)(vb);
            const short8 v23 = *(const short8*)(vb + 8);

            // P -> bf16 A-frag: round (+0x8000) then take hi16 pairs via v_perm
            const unsigned int c0 = __builtin_bit_cast(unsigned int, S[bb][0] * fr[0]) + 0x8000u;
            const unsigned int c1 = __builtin_bit_cast(unsigned int, S[bb][1] * fr[1]) + 0x8000u;
            const unsigned int c2 = __builtin_bit_cast(unsigned int, S[bb][2] * fr[2]) + 0x8000u;
            const unsigned int c3 = __builtin_bit_cast(unsigned int, S[bb][3] * fr[3]) + 0x8000u;
            int2v pp;
            pp[0] = (int)__builtin_amdgcn_perm(c1, c0, 0x07060302u);
            pp[1] = (int)__builtin_amdgcn_perm(c3, c2, 0x07060302u);
            const short4v af = __builtin_bit_cast(short4v, pp);

            const short4v vb0 = __builtin_shufflevector(v01, v01, 0, 1, 2, 3);
            const short4v vb1 = __builtin_shufflevector(v01, v01, 4, 5, 6, 7);
            const short4v vb2 = __builtin_shufflevector(v23, v23, 0, 1, 2, 3);
            const short4v vb3 = __builtin_shufflevector(v23, v23, 4, 5, 6, 7);

            O[bb][0] = MFMA16(af, vb0, O[bb][0]);
            O[bb][1] = MFMA16(af, vb1, O[bb][1]);
            O[bb][2] = MFMA16(af, vb2, O[bb][2]);
            O[bb][3] = MFMA16(af, vb3, O[bb][3]);
        }
        // single barrier per iter; dl double-buffer makes next-iter writes safe
    }

    // guard MFMA->VALU read (needed for asm fallback; cheap otherwise)
    asm volatile("s_nop 7\n\ts_nop 7" :::);

    // ---- merge k-chunk partials ----
    #pragma unroll
    for (int bb = 0; bb < 4; ++bb)
        #pragma unroll
        for (int dt = 0; dt < 4; ++dt)
            #pragma unroll
            for (int r = 0; r < 4; ++r)
                unsafeAtomicAdd(Og + ((size_t)((b0 + bb) * SEQ + qt * 16 + g * 4 + r)) * DIM
                                    + dt * 16 + a,
                                O[bb][dt][r]);
}

// ---------------- fallback (ws too small): naive fp32 ----------------
__global__ __launch_bounds__(512)
void dpa_naive(const float* __restrict__ Q, const float* __restrict__ K,
               const float* __restrict__ V, float* __restrict__ out) {
    __shared__ float attn_lds[BATCH][8][64];
    const int tid = threadIdx.x;
    const int lane_k = tid & 63, row_q = tid >> 6, lane_d = tid & 63;
    const int q0 = blockIdx.x * 8;
    float acc[BATCH];
    #pragma unroll
    for (int b = 0; b < BATCH; ++b) acc[b] = 0.0f;
    for (int k0 = 0; k0 < SEQ; k0 += 64) {
        float s[BATCH];
        #pragma unroll
        for (int b = 0; b < BATCH; ++b) {
            const float4* qrow = (const float4*)(Q + ((size_t)b * SEQ + (q0 + row_q)) * DIM);
            const float4* krow = (const float4*)(K + ((size_t)b * SEQ + (k0 + lane_k)) * DIM);
            float a0 = 0.f;
            #pragma unroll
            for (int d4 = 0; d4 < 16; ++d4) {
                float4 qa = qrow[d4]; float4 kb = krow[d4];
                a0 += qa.x*kb.x + qa.y*kb.y + qa.z*kb.z + qa.w*kb.w;
            }
            s[b] = a0 * 0.125f;
        }
        float m = s[0];
        #pragma unroll
        for (int b = 1; b < BATCH; ++b) m = fmaxf(m, s[b]);
        float den = 0.f;
        #pragma unroll
        for (int b = 0; b < BATCH; ++b) { s[b] = __expf(s[b] - m); den += s[b]; }
        const float inv = 1.0f / den;
        #pragma unroll
        for (int b = 0; b < BATCH; ++b) attn_lds[b][row_q][lane_k] = s[b] * inv;
        __syncthreads();
        #pragma unroll
        for (int b = 0; b < BATCH; ++b) {
            const float* vbase = V + ((size_t)b * SEQ + k0) * DIM + lane_d;
            float acc2 = 0.f;
            #pragma unroll 8
            for (int kk = 0; kk < 64; ++kk) acc2 += attn_lds[b][row_q][kk] * vbase[(size_t)kk * DIM];
            acc[b] += acc2;
        }
        __syncthreads();
    }
    #pragma unroll
    for (int b = 0; b < BATCH; ++b)
        out[((size_t)b * SEQ + (q0 + row_q)) * DIM + lane_d] = acc[b];
}

extern "C" void kernel_launch(void* const* d_in, const int* in_sizes, int n_in,
                              void* d_out, int out_size, void* d_ws, size_t ws_size,
                              hipStream_t stream) {
    const float* Q = (const float*)d_in[0];
    const float* K = (const float*)d_in[1];
    const float* V = (const float*)d_in[2];
    float* out = (float*)d_out;

    if (ws_size < WS_NEED) {
        dpa_naive<<<dim3(SEQ / 8), dim3(512), 0, stream>>>(Q, K, V, out);
        return;
    }
    unsigned short* ws = (unsigned short*)d_ws;
    hipMemsetAsync(d_out, 0, (size_t)out_size * sizeof(float), stream);
    convert_kernel<<<dim3(2560), dim3(256), 0, stream>>>(Q, K, V, ws);
    dpa_main<<<dim3(1024), dim3(256), 0, stream>>>(ws, ws + 2097152, ws + 4194304, out);
}

// Round 5
// 90.638 us; speedup vs baseline: 168.7325x; 1.6790x over previous
//
#include <hip/hip_runtime.h>
#include <hip/hip_bf16.h>

typedef __attribute__((ext_vector_type(8))) short short8;
typedef __attribute__((ext_vector_type(4))) short short4v;
typedef __attribute__((ext_vector_type(2))) int   int2v;
typedef __attribute__((ext_vector_type(4))) float floatx4;

#define BATCH 16
#define SEQ   2048
#define DIM   64
#define QSCALE 0.18033688011112042f   /* 0.125 * log2(e) : softmax in exp2 domain */
#define WS_NEED (12u*1024u*1024u)

__device__ __forceinline__ unsigned short f2bf(float f) {
    return __builtin_bit_cast(unsigned short, __float2bfloat16(f));
}

// ---- K=16 bf16 MFMA: prefer intrinsic, fall back to inline asm ----
#if defined(__has_builtin)
#if __has_builtin(__builtin_amdgcn_mfma_f32_16x16x16bf16_1k)
#define MFMA16(A,B,C) __builtin_amdgcn_mfma_f32_16x16x16bf16_1k(A,B,C,0,0,0)
#elif __has_builtin(__builtin_amdgcn_mfma_f32_16x16x16_bf16)
#define MFMA16(A,B,C) __builtin_amdgcn_mfma_f32_16x16x16_bf16(A,B,C,0,0,0)
#endif
#endif
#ifndef MFMA16
__device__ __forceinline__ floatx4 mfma16_asm(short4v a, short4v b, floatx4 c) {
    asm volatile("s_nop 1\n\tv_mfma_f32_16x16x16_bf16 %0, %1, %2, %0"
                 : "+v"(c) : "v"(a), "v"(b));
    return c;
}
#define MFMA16(A,B,C) mfma16_asm(A,B,C)
#endif

// ---------------- convert: fp32 -> bf16 MFMA-frag layouts ----------------
// Qw [16][128 t16][2 st][64 l][8p] = Q[b][t16*16+a][st*32+g*8+p] * QSCALE  (a=l&15,g=l>>4)
// Kw same (scale 1).
// Vw [16][128 kt][64 l][4 dt][4p] = V[b][kt*16+g*4+p][dt*16+a]   (B frag for 16x16x16)
__global__ __launch_bounds__(256)
void convert_kernel(const float* __restrict__ Q, const float* __restrict__ K,
                    const float* __restrict__ V, unsigned short* __restrict__ ws) {
    const int t = blockIdx.x * 256 + threadIdx.x;   // 0..655359
    if (t < 524288) {
        const int region = t >> 18;                 // 0=Q 1=K
        const int r = t & 262143;
        const int b = r >> 14;
        const int rem = r & 16383;
        const int t16 = rem >> 7;
        const int st  = (rem >> 6) & 1;
        const int l   = rem & 63;
        const int a = l & 15, g = l >> 4;
        const float* src = (region == 0 ? Q : K) +
            ((size_t)(b * SEQ + t16 * 16 + a)) * DIM + st * 32 + g * 8;
        const float s = (region == 0) ? QSCALE : 1.0f;
        short8 o;
        #pragma unroll
        for (int p = 0; p < 8; ++p) o[p] = (short)f2bf(src[p] * s);
        *(short8*)(ws + (size_t)region * 2097152 + (size_t)r * 8) = o;
    } else {
        const int r = t - 524288;                   // 0..131071 = [b][kt][l]
        const int b  = r >> 13;
        const int kt = (r >> 6) & 127;
        const int l  = r & 63;
        const int a = l & 15, g = l >> 4;
        const float* src = V + ((size_t)(b * SEQ + kt * 16 + g * 4)) * DIM + a;
        short8 o0, o1;
        #pragma unroll
        for (int dt = 0; dt < 2; ++dt)
            #pragma unroll
            for (int p = 0; p < 4; ++p)
                o0[dt * 4 + p] = (short)f2bf(src[(size_t)p * DIM + dt * 16]);
        #pragma unroll
        for (int dt = 2; dt < 4; ++dt)
            #pragma unroll
            for (int p = 0; p < 4; ++p)
                o1[(dt - 2) * 4 + p] = (short)f2bf(src[(size_t)p * DIM + dt * 16]);
        unsigned short* dst = ws + 4194304 + (size_t)r * 16;
        *(short8*)(dst)     = o0;
        *(short8*)(dst + 8) = o1;
    }
}

// ---------------- main: softmax-over-batch attention ----------------
// grid 512 = 128 q-tiles(16) x 4 k-chunks(512).  ch = bx&3 -> chunk per XCD-pair.
// block 256 = 4 waves = 4 batch-quarters. Swapped QK^T (mfma(K,Q)) puts
// P^T[k=g*4+r][q=a] in registers == the A-frag of 16x16x16 PV.
// Pipelined: K(it+1) and V(it) loads issue before the (single) barrier, so
// L2 latency hides under softmax+barrier+combine. Only the denominator
// crosses waves (8 KB double-buffered dl, swizzled conflict-free writes).
__global__ __launch_bounds__(256)
void dpa_main(const unsigned short* __restrict__ Qw, const unsigned short* __restrict__ Kw,
              const unsigned short* __restrict__ Vw, float* __restrict__ Og) {
    __shared__ __align__(16) float dl[2][4][64][4];   // [buf][r][l][w-slot] : 8 KB

    const int tid = threadIdx.x;
    const int l = tid & 63;
    const int w = tid >> 6;            // batch-quarter 0..3
    const int a = l & 15, g = l >> 4;
    const int bx = blockIdx.x;
    const int ch = bx & 3;
    const int qt = bx >> 2;
    const int b0 = w * 4;
    const int wsw = w ^ ((l >> 3) & 3);   // swizzled slot: write 2-way-free; sum is perm-invariant

    // per-lane base pointers (element = ushort)
    const unsigned short* Qb = Qw + (size_t)b0 * 131072 + qt * 1024 + l * 8;
    const unsigned short* Kb = Kw + (size_t)b0 * 131072 + l * 8;
    const unsigned short* Vb = Vw + (size_t)b0 * 131072 + l * 16;

    // Q fragments in registers (iteration-invariant)
    short8 Qf[4][2];
    #pragma unroll
    for (int bb = 0; bb < 4; ++bb)
        #pragma unroll
        for (int st = 0; st < 2; ++st)
            Qf[bb][st] = *(const short8*)(Qb + bb * 131072 + st * 512);

    // prologue: K fragments for it=0
    short8 Kf[4][2];
    #pragma unroll
    for (int bb = 0; bb < 4; ++bb)
        #pragma unroll
        for (int st = 0; st < 2; ++st)
            Kf[bb][st] = *(const short8*)(Kb + bb * 131072 + (ch * 32) * 1024 + st * 512);

    floatx4 O[4][4];
    #pragma unroll
    for (int bb = 0; bb < 4; ++bb)
        #pragma unroll
        for (int dt = 0; dt < 4; ++dt) O[bb][dt] = (floatx4)0.0f;

    for (int it = 0; it < 32; ++it) {
        const int buf = it & 1;
        const int kt = ch * 32 + it;

        // ---- QK^T (swapped): S^T[k=g*4+r][q=a], scores pre-scaled via Q ----
        floatx4 S[4];
        #pragma unroll
        for (int bb = 0; bb < 4; ++bb) {
            floatx4 s = (floatx4)0.0f;
            s = __builtin_amdgcn_mfma_f32_16x16x32_bf16(Kf[bb][0], Qf[bb][0], s, 0, 0, 0);
            s = __builtin_amdgcn_mfma_f32_16x16x32_bf16(Kf[bb][1], Qf[bb][1], s, 0, 0, 0);
            S[bb] = s;
        }

        // ---- prefetch K(it+1): lands during softmax+barrier+PV ----
        const int ktn = (it < 31) ? (kt + 1) : kt;
        #pragma unroll
        for (int bb = 0; bb < 4; ++bb)
            #pragma unroll
            for (int st = 0; st < 2; ++st)
                Kf[bb][st] = *(const short8*)(Kb + bb * 131072 + ktn * 1024 + st * 512);

        // ---- V(it) loads: consumed only after the barrier ----
        short8 V01[4], V23[4];
        #pragma unroll
        for (int bb = 0; bb < 4; ++bb) {
            const unsigned short* vp = Vb + bb * 131072 + kt * 1024;
            V01[bb] = *(const short8*)(vp);
            V23[bb] = *(const short8*)(vp + 8);
        }

        // ---- local softmax partial (no max-subtraction: |S|<~10 in log2 domain) ----
        #pragma unroll
        for (int r = 0; r < 4; ++r) {
            float e0 = exp2f(S[0][r]);
            float e1 = exp2f(S[1][r]);
            float e2 = exp2f(S[2][r]);
            float e3 = exp2f(S[3][r]);
            S[0][r] = e0; S[1][r] = e1; S[2][r] = e2; S[3][r] = e3;
            dl[buf][r][l][wsw] = (e0 + e1) + (e2 + e3);
        }
        __syncthreads();

        // ---- combine denominators (1 x b128 per r, conflict-free) ----
        float fr[4];
        #pragma unroll
        for (int r = 0; r < 4; ++r) {
            const floatx4 t = *(const floatx4*)&dl[buf][r][l][0];
            fr[r] = __builtin_amdgcn_rcpf((t[0] + t[1]) + (t[2] + t[3]));
        }

        // ---- finalize P (bf16 pack via round+perm) + PV ----
        #pragma unroll
        for (int bb = 0; bb < 4; ++bb) {
            const unsigned int c0 = __builtin_bit_cast(unsigned int, S[bb][0] * fr[0]) + 0x8000u;
            const unsigned int c1 = __builtin_bit_cast(unsigned int, S[bb][1] * fr[1]) + 0x8000u;
            const unsigned int c2 = __builtin_bit_cast(unsigned int, S[bb][2] * fr[2]) + 0x8000u;
            const unsigned int c3 = __builtin_bit_cast(unsigned int, S[bb][3] * fr[3]) + 0x8000u;
            int2v pp;
            pp[0] = (int)__builtin_amdgcn_perm(c1, c0, 0x07060302u);
            pp[1] = (int)__builtin_amdgcn_perm(c3, c2, 0x07060302u);
            const short4v af = __builtin_bit_cast(short4v, pp);

            const short4v vb0 = __builtin_shufflevector(V01[bb], V01[bb], 0, 1, 2, 3);
            const short4v vb1 = __builtin_shufflevector(V01[bb], V01[bb], 4, 5, 6, 7);
            const short4v vb2 = __builtin_shufflevector(V23[bb], V23[bb], 0, 1, 2, 3);
            const short4v vb3 = __builtin_shufflevector(V23[bb], V23[bb], 4, 5, 6, 7);

            O[bb][0] = MFMA16(af, vb0, O[bb][0]);
            O[bb][1] = MFMA16(af, vb1, O[bb][1]);
            O[bb][2] = MFMA16(af, vb2, O[bb][2]);
            O[bb][3] = MFMA16(af, vb3, O[bb][3]);
        }
        // single barrier/iter; dl double-buffer makes next-iter writes safe
    }

    // guard MFMA->VALU read (needed for asm fallback; cheap otherwise)
    asm volatile("s_nop 7\n\ts_nop 7" :::);

    // ---- merge k-chunk partials ----
    #pragma unroll
    for (int bb = 0; bb < 4; ++bb)
        #pragma unroll
        for (int dt = 0; dt < 4; ++dt)
            #pragma unroll
            for (int r = 0; r < 4; ++r)
                unsafeAtomicAdd(Og + ((size_t)((b0 + bb) * SEQ + qt * 16 + g * 4 + r)) * DIM
                                    + dt * 16 + a,
                                O[bb][dt][r]);
}

// ---------------- fallback (ws too small): naive fp32 ----------------
__global__ __launch_bounds__(512)
void dpa_naive(const float* __restrict__ Q, const float* __restrict__ K,
               const float* __restrict__ V, float* __restrict__ out) {
    __shared__ float attn_lds[BATCH][8][64];
    const int tid = threadIdx.x;
    const int lane_k = tid & 63, row_q = tid >> 6, lane_d = tid & 63;
    const int q0 = blockIdx.x * 8;
    float acc[BATCH];
    #pragma unroll
    for (int b = 0; b < BATCH; ++b) acc[b] = 0.0f;
    for (int k0 = 0; k0 < SEQ; k0 += 64) {
        float s[BATCH];
        #pragma unroll
        for (int b = 0; b < BATCH; ++b) {
            const float4* qrow = (const float4*)(Q + ((size_t)b * SEQ + (q0 + row_q)) * DIM);
            const float4* krow = (const float4*)(K + ((size_t)b * SEQ + (k0 + lane_k)) * DIM);
            float a0 = 0.f;
            #pragma unroll
            for (int d4 = 0; d4 < 16; ++d4) {
                float4 qa = qrow[d4]; float4 kb = krow[d4];
                a0 += qa.x*kb.x + qa.y*kb.y + qa.z*kb.z + qa.w*kb.w;
            }
            s[b] = a0 * 0.125f;
        }
        float m = s[0];
        #pragma unroll
        for (int b = 1; b < BATCH; ++b) m = fmaxf(m, s[b]);
        float den = 0.f;
        #pragma unroll
        for (int b = 0; b < BATCH; ++b) { s[b] = __expf(s[b] - m); den += s[b]; }
        const float inv = 1.0f / den;
        #pragma unroll
        for (int b = 0; b < BATCH; ++b) attn_lds[b][row_q][lane_k] = s[b] * inv;
        __syncthreads();
        #pragma unroll
        for (int b = 0; b < BATCH; ++b) {
            const float* vbase = V + ((size_t)b * SEQ + k0) * DIM + lane_d;
            float acc2 = 0.f;
            #pragma unroll 8
            for (int kk = 0; kk < 64; ++kk) acc2 += attn_lds[b][row_q][kk] * vbase[(size_t)kk * DIM];
            acc[b] += acc2;
        }
        __syncthreads();
    }
    #pragma unroll
    for (int b = 0; b < BATCH; ++b)
        out[((size_t)b * SEQ + (q0 + row_q)) * DIM + lane_d] = acc[b];
}

extern "C" void kernel_launch(void* const* d_in, const int* in_sizes, int n_in,
                              void* d_out, int out_size, void* d_ws, size_t ws_size,
                              hipStream_t stream) {
    const float* Q = (const float*)d_in[0];
    const float* K = (const float*)d_in[1];
    const float* V = (const float*)d_in[2];
    float* out = (float*)d_out;

    if (ws_size < WS_NEED) {
        dpa_naive<<<dim3(SEQ / 8), dim3(512), 0, stream>>>(Q, K, V, out);
        return;
    }
    unsigned short* ws = (unsigned short*)d_ws;
    hipMemsetAsync(d_out, 0, (size_t)out_size * sizeof(float), stream);
    convert_kernel<<<dim3(2560), dim3(256), 0, stream>>>(Q, K, V, ws);
    dpa_main<<<dim3(512), dim3(256), 0, stream>>>(ws, ws + 2097152, ws + 4194304, out);
}